// Round 1
// baseline (2467.048 us; speedup 1.0000x reference)
//
#include <hip/hip_runtime.h>
#include <hip/hip_bf16.h>

#define TT    512
#define ISZ   9
#define HH    50
#define KA    60          // augmented K: 50 h + 9 x + 1 bias
#define NB    16          // batch elements per block
#define NTH   512         // 8 waves
#define RPW   25          // gate rows per wave (200/8)
#define NROWS 200         // 4*H gate rows

__device__ __forceinline__ float sigm_f(float z) {
  float e = __builtin_amdgcn_exp2f(z * -1.44269504088896340736f);
  return __builtin_amdgcn_rcpf(1.0f + e);
}
__device__ __forceinline__ float tanh_f(float z) {
  float e = __builtin_amdgcn_exp2f(z * 2.88539008177792681472f);
  return fmaf(-2.0f, __builtin_amdgcn_rcpf(1.0f + e), 1.0f);
}

__global__ __launch_bounds__(NTH, 1) void lstm_fused(
    const float* __restrict__ x,
    const float* __restrict__ w_ih,
    const float* __restrict__ w_hh,
    const float* __restrict__ b_ih,
    const float* __restrict__ b_hh,
    const float* __restrict__ fc_w,
    const float* __restrict__ fc_b,
    float* __restrict__ out) {
  // LDS: 48064 + 3904 + 12800 = 64768 B  (fits 64 KiB static limit)
  __shared__ float Wa[NROWS * KA + 16];   // [200][60] = [w_hh | w_ih | bias], +pad for s=3 overread
  __shared__ float ha[NB * KA + 16];      // [16][60]  = [h | x(t) | 1], +pad
  __shared__ float gbuf[NROWS * NB];      // gate pre-activations [200][16]

  const int tid = threadIdx.x;
  const int b0  = blockIdx.x * NB;

  // ---- build augmented weights in LDS
  for (int i = tid; i < NROWS * KA; i += NTH) {
    const int row = i / KA;
    const int k   = i - row * KA;
    float v;
    if (k < HH)            v = w_hh[row * HH + k];
    else if (k < HH + ISZ) v = w_ih[row * ISZ + (k - HH)];
    else                   v = b_ih[row] + b_hh[row];
    Wa[i] = v;
  }
  if (tid < 16) Wa[NROWS * KA + tid] = 0.0f;

  // ---- init state: h = 0 | x(t=0) | 1  (pad zeroed)
  for (int i = tid; i < NB * KA + 16; i += NTH) {
    float v = 0.0f;
    if (i < NB * KA) {
      const int b = i / KA;
      const int k = i - b * KA;
      if (k >= HH && k < HH + ISZ)
        v = x[(size_t)(b0 + b) * (TT * ISZ) + (k - HH)];
      else if (k == KA - 1)
        v = 1.0f;
    }
    ha[i] = v;
  }

  // phase-1 lane mapping: lane = b(16) x k-quarter s(4); wave owns 25 rows
  const int lane    = tid & 63;
  const int bl      = lane & 15;
  const int s       = lane >> 4;
  const int ko      = s << 4;               // k offset: 0,16,32,48
  const int rowbase = RPW * (tid >> 6);

  // phase-2 (update) mapping: thread -> (b, j) items, c state in registers
  const int ub = tid & 15;
  const int uj = tid >> 4;                  // 0..31
  const bool has2 = (tid < 288);            // second item j+32 < 50
  float c0 = 0.0f, c1 = 0.0f;

  // x prefetch mapping: 144 threads load x[b][t+1][xi]
  const int xb = tid / ISZ;
  const int xi = tid - xb * ISZ;
  const bool xload = (tid < NB * ISZ);

  __syncthreads();

  for (int t = 0; t < TT; ++t) {
    // prefetch next timestep's x into registers (hidden under dot loop)
    float xreg = 0.0f;
    if (xload && (t + 1) < TT)
      xreg = x[(size_t)(b0 + xb) * (TT * ISZ) + (size_t)(t + 1) * ISZ + xi];

    // load this lane's k-quarter of [h|x|1]  (4x ds_read_b128, 2-way banks)
    const float4* hp = reinterpret_cast<const float4*>(&ha[bl * KA + ko]);
    float4 q0 = hp[0], q1 = hp[1], q2 = hp[2], q3 = hp[3];
    if (s == 3) { q3.x = 0.0f; q3.y = 0.0f; q3.z = 0.0f; q3.w = 0.0f; }

#pragma unroll 5
    for (int rr = 0; rr < RPW; ++rr) {
      const int row = rowbase + rr;
      const float4* wp = reinterpret_cast<const float4*>(&Wa[row * KA + ko]);
      const float4 w0 = wp[0], w1 = wp[1], w2 = wp[2], w3 = wp[3];
      float a0 = w0.x * q0.x, a1 = w0.y * q0.y;
      a0 = fmaf(w0.z, q0.z, a0); a1 = fmaf(w0.w, q0.w, a1);
      a0 = fmaf(w1.x, q1.x, a0); a1 = fmaf(w1.y, q1.y, a1);
      a0 = fmaf(w1.z, q1.z, a0); a1 = fmaf(w1.w, q1.w, a1);
      a0 = fmaf(w2.x, q2.x, a0); a1 = fmaf(w2.y, q2.y, a1);
      a0 = fmaf(w2.z, q2.z, a0); a1 = fmaf(w2.w, q2.w, a1);
      a0 = fmaf(w3.x, q3.x, a0); a1 = fmaf(w3.y, q3.y, a1);
      a0 = fmaf(w3.z, q3.z, a0); a1 = fmaf(w3.w, q3.w, a1);
      float acc = a0 + a1;
      acc += __shfl_xor(acc, 16);           // combine k-quarters
      acc += __shfl_xor(acc, 32);
      if (s == (rr & 3)) gbuf[row * NB + bl] = acc;  // rotate writer lane set
    }
    __syncthreads();

    // stage x(t+1) into augmented state
    if (xload && (t + 1) < TT) ha[xb * KA + HH + xi] = xreg;

    // gate nonlinearities + c/h update; c persists in registers
    {
      const float gi = gbuf[uj * NB + ub];
      const float gf = gbuf[(HH + uj) * NB + ub];
      const float gg = gbuf[(2 * HH + uj) * NB + ub];
      const float go = gbuf[(3 * HH + uj) * NB + ub];
      const float iv = sigm_f(gi), fv = sigm_f(gf);
      const float gv = tanh_f(gg), ov = sigm_f(go);
      c0 = fmaf(fv, c0, iv * gv);
      ha[ub * KA + uj] = ov * tanh_f(c0);
    }
    if (has2) {
      const int j2 = uj + 32;
      const float gi = gbuf[j2 * NB + ub];
      const float gf = gbuf[(HH + j2) * NB + ub];
      const float gg = gbuf[(2 * HH + j2) * NB + ub];
      const float go = gbuf[(3 * HH + j2) * NB + ub];
      const float iv = sigm_f(gi), fv = sigm_f(gf);
      const float gv = tanh_f(gg), ov = sigm_f(go);
      c1 = fmaf(fv, c1, iv * gv);
      ha[ub * KA + j2] = ov * tanh_f(c1);
    }
    __syncthreads();
  }

  // final FC: out[b] = h_last . fc_w + fc_b
  if (tid < NB) {
    float a = fc_b[0];
#pragma unroll
    for (int j = 0; j < HH; ++j)
      a = fmaf(ha[tid * KA + j], fc_w[j], a);
    out[b0 + tid] = a;
  }
}

extern "C" void kernel_launch(void* const* d_in, const int* in_sizes, int n_in,
                              void* d_out, int out_size, void* d_ws, size_t ws_size,
                              hipStream_t stream) {
  const float* x    = (const float*)d_in[0];
  const float* w_ih = (const float*)d_in[1];
  const float* w_hh = (const float*)d_in[2];
  const float* b_ih = (const float*)d_in[3];
  const float* b_hh = (const float*)d_in[4];
  const float* fc_w = (const float*)d_in[5];
  const float* fc_b = (const float*)d_in[6];
  float* out = (float*)d_out;
  const int Btot = in_sizes[0] / (TT * ISZ);   // 4096
  dim3 grid(Btot / NB), block(NTH);
  hipLaunchKernelGGL(lstm_fused, grid, block, 0, stream,
                     x, w_ih, w_hh, b_ih, b_hh, fc_w, fc_b, out);
}

// Round 2
// 298.132 us; speedup vs baseline: 8.2750x; 8.2750x over previous
//
#include <hip/hip_runtime.h>
#include <hip/hip_bf16.h>

#define TT    512
#define ISZ   9
#define HH    50
#define NB    16      // batches per block
#define NTH   512     // 8 waves
#define KDIM  128     // augmented K: [h_hi 0-51 | h_lo 52-103 | x_hi 104-112 | bias_hi 113 | bias_lo 114 | x_lo 115-123 | 0 124-127]

typedef __bf16 bf16x8_t __attribute__((ext_vector_type(8)));
typedef float  f32x4_t  __attribute__((ext_vector_type(4)));

__device__ __forceinline__ unsigned short bf16_rne(float f) {
  unsigned u = __builtin_bit_cast(unsigned, f);
  unsigned r = (u + 0x7FFFu + ((u >> 16) & 1u)) >> 16;
  return (unsigned short)r;
}
__device__ __forceinline__ float bf16_to_f(unsigned short b) {
  unsigned u = ((unsigned)b) << 16;
  return __builtin_bit_cast(float, u);
}
__device__ __forceinline__ float sigm_f(float z) {
  float e = __builtin_amdgcn_exp2f(z * -1.44269504088896340736f);
  return __builtin_amdgcn_rcpf(1.0f + e);
}
__device__ __forceinline__ float tanh_f(float z) {
  float e = __builtin_amdgcn_exp2f(z * 2.88539008177792681472f);
  return fmaf(-2.0f, __builtin_amdgcn_rcpf(1.0f + e), 1.0f);
}
// byte offset of element (b, k) in a [16][128] bf16 buffer, XOR-swizzled so
// B-fragment ds_read_b128 (16 lanes share kq, differ in b) hits 32 banks 2-way.
__device__ __forceinline__ int swz(int b, int k) {
  return ((b << 8) + (k << 1)) ^ ((b & 7) << 4);
}

__global__ __launch_bounds__(NTH, 2) void lstm_mfma(
    const float* __restrict__ x,
    const float* __restrict__ w_ih,
    const float* __restrict__ w_hh,
    const float* __restrict__ b_ih,
    const float* __restrict__ b_hh,
    const float* __restrict__ fc_w,
    const float* __restrict__ fc_b,
    float* __restrict__ out) {
  __shared__ __align__(16) unsigned short hbuf[2][NB * KDIM];  // 8 KiB double-buffered B operand
  __shared__ float redbuf[8][NB];

  const int tid = threadIdx.x;
  const int w   = tid >> 6;          // wave id 0..7
  const int l   = tid & 63;
  const int lb  = l & 15;            // batch column
  const int kq  = l >> 4;            // k-quarter 0..3
  const int b0  = blockIdx.x * NB;
  const bool has2 = (w < 5);         // 13 tiles: wave w owns tile w, and 8+w if w<5
  const int tile0 = w, tile1 = 8 + w;

  // ---- zero both h buffers
  for (int i = tid; i < (2 * NB * KDIM) / 2; i += NTH)
    reinterpret_cast<unsigned*>(hbuf)[i] = 0u;
  __syncthreads();

  // ---- bias-one rows (k=113,114 hold B=1.0 forever, both buffers)
  if (tid < NB) {
#pragma unroll
    for (int bb = 0; bb < 2; ++bb) {
      *(unsigned short*)((char*)hbuf[bb] + swz(tid, 113)) = 0x3F80;
      *(unsigned short*)((char*)hbuf[bb] + swz(tid, 114)) = 0x3F80;
    }
  }

  // ---- x(t=0) hi/lo into buf 0
  const int xb = tid / ISZ, xi = tid - xb * ISZ;
  const bool xact = (tid < NB * ISZ);
  if (xact) {
    float xv = x[(size_t)(b0 + xb) * (TT * ISZ) + xi];
    unsigned short hi = bf16_rne(xv);
    unsigned short lo = bf16_rne(xv - bf16_to_f(hi));
    *(unsigned short*)((char*)hbuf[0] + swz(xb, 104 + xi)) = hi;
    *(unsigned short*)((char*)hbuf[0] + swz(xb, 115 + xi)) = lo;
  }

  // ---- gather static A fragments into registers (one time).
  // Row permutation r' = 4*j + gate, so C/D layout (row=(lane>>4)*4+reg) gives
  // each lane the (i,f,g,o) quad of one j.  A-frag: lane holds A[row=l&15][k=8*kq+e].
  bf16x8_t afrag[2][4];
#pragma unroll
  for (int tt = 0; tt < 2; ++tt) {
    const int tile = tt ? tile1 : tile0;
    const bool act = (tt == 0) || has2;
    const int rp  = tile * 16 + lb;     // permuted row index
    const int j   = rp >> 2;
    const int g   = rp & 3;
    const int row = g * HH + j;         // original [i,f,g,o]-block row
    const bool live = act && (j < HH);
    float bsum = live ? (b_ih[row] + b_hh[row]) : 0.0f;
    unsigned short bs_hi = bf16_rne(bsum);
    float bs_lo = bsum - bf16_to_f(bs_hi);
#pragma unroll
    for (int ks = 0; ks < 4; ++ks) {
#pragma unroll
      for (int e = 0; e < 8; ++e) {
        const int K = ks * 32 + kq * 8 + e;
        unsigned short bits = 0;
        if (live) {
          if (K < 52)        { if (K < HH)        bits = bf16_rne(w_hh[row * HH + K]); }
          else if (K < 104)  { int kk = K - 52; if (kk < HH) bits = bf16_rne(w_hh[row * HH + kk]); }
          else if (K < 113)  bits = bf16_rne(w_ih[row * ISZ + (K - 104)]);
          else if (K == 113) bits = bs_hi;
          else if (K == 114) bits = bf16_rne(bs_lo);
          else if (K < 124)  bits = bf16_rne(w_ih[row * ISZ + (K - 115)]);
        }
        afrag[tt][ks][e] = __builtin_bit_cast(__bf16, bits);
      }
    }
  }

  float c0 = 0.0f, c1 = 0.0f, h0 = 0.0f, h1 = 0.0f;

  for (int t = 0; t < TT; ++t) {
    // prefetch x(t+1) (f32) — latency hides under MFMA+update
    float xv = 0.0f;
    if (xact && (t + 1) < TT)
      xv = x[(size_t)(b0 + xb) * (TT * ISZ) + (size_t)(t + 1) * ISZ + xi];

    __syncthreads();   // buf[t&1] (written during step t-1) now visible

    const char* hb = (const char*)hbuf[t & 1];
    bf16x8_t bfr[4];
#pragma unroll
    for (int ks = 0; ks < 4; ++ks) {
      const int off = ((lb << 8) + ks * 64 + kq * 16) ^ ((lb & 7) << 4);
      bfr[ks] = *(const bf16x8_t*)(hb + off);
    }

    f32x4_t acc0 = {0.f, 0.f, 0.f, 0.f};
    f32x4_t acc1 = {0.f, 0.f, 0.f, 0.f};
#pragma unroll
    for (int ks = 0; ks < 4; ++ks) {
      acc0 = __builtin_amdgcn_mfma_f32_16x16x32_bf16(afrag[0][ks], bfr[ks], acc0, 0, 0, 0);
      if (has2)
        acc1 = __builtin_amdgcn_mfma_f32_16x16x32_bf16(afrag[1][ks], bfr[ks], acc1, 0, 0, 0);
    }

    char* hbn = (char*)hbuf[(t + 1) & 1];
    {
      const float iv = sigm_f(acc0[0]), fv = sigm_f(acc0[1]);
      const float gv = tanh_f(acc0[2]), ov = sigm_f(acc0[3]);
      c0 = fmaf(fv, c0, iv * gv);
      h0 = ov * tanh_f(c0);
      const int j = tile0 * 4 + kq;
      unsigned short hi = bf16_rne(h0);
      unsigned short lo = bf16_rne(h0 - bf16_to_f(hi));
      *(unsigned short*)(hbn + swz(lb, j))      = hi;
      *(unsigned short*)(hbn + swz(lb, 52 + j)) = lo;
    }
    if (has2) {
      const float iv = sigm_f(acc1[0]), fv = sigm_f(acc1[1]);
      const float gv = tanh_f(acc1[2]), ov = sigm_f(acc1[3]);
      c1 = fmaf(fv, c1, iv * gv);
      h1 = ov * tanh_f(c1);
      const int j = tile1 * 4 + kq;
      unsigned short hi = bf16_rne(h1);
      unsigned short lo = bf16_rne(h1 - bf16_to_f(hi));
      *(unsigned short*)(hbn + swz(lb, j))      = hi;
      *(unsigned short*)(hbn + swz(lb, 52 + j)) = lo;
    }
    if (xact && (t + 1) < TT) {
      unsigned short hi = bf16_rne(xv);
      unsigned short lo = bf16_rne(xv - bf16_to_f(hi));
      *(unsigned short*)(hbn + swz(xb, 104 + xi)) = hi;
      *(unsigned short*)(hbn + swz(xb, 115 + xi)) = lo;
    }
  }

  // ---- FC epilogue: out[b] = sum_j h_last[j,b]*fc_w[j] + fc_b
  float p = 0.0f;
  { const int j = tile0 * 4 + kq; if (j < HH) p += h0 * fc_w[j]; }
  if (has2) { const int j = tile1 * 4 + kq; if (j < HH) p += h1 * fc_w[j]; }
  p += __shfl_xor(p, 16);
  p += __shfl_xor(p, 32);
  if (l < NB) redbuf[w][l] = p;
  __syncthreads();
  if (tid < NB) {
    float a = fc_b[0];
#pragma unroll
    for (int ww = 0; ww < 8; ++ww) a += redbuf[ww][tid];
    out[b0 + tid] = a;
  }
}

extern "C" void kernel_launch(void* const* d_in, const int* in_sizes, int n_in,
                              void* d_out, int out_size, void* d_ws, size_t ws_size,
                              hipStream_t stream) {
  const float* x    = (const float*)d_in[0];
  const float* w_ih = (const float*)d_in[1];
  const float* w_hh = (const float*)d_in[2];
  const float* b_ih = (const float*)d_in[3];
  const float* b_hh = (const float*)d_in[4];
  const float* fc_w = (const float*)d_in[5];
  const float* fc_b = (const float*)d_in[6];
  float* out = (float*)d_out;
  const int Btot = in_sizes[0] / (TT * ISZ);   // 4096
  dim3 grid(Btot / NB), block(NTH);
  hipLaunchKernelGGL(lstm_mfma, grid, block, 0, stream,
                     x, w_ih, w_hh, b_ih, b_hh, fc_w, fc_b, out);
}

// Round 3
// 281.042 us; speedup vs baseline: 8.7782x; 1.0608x over previous
//
#include <hip/hip_runtime.h>
#include <hip/hip_bf16.h>

#define TT    512
#define ISZ   9
#define HH    50
#define NB    16      // batches per block
#define NTH   512     // 8 waves
#define KDIM  128
// K layout (bf16 elements, per batch-column):
//   k=2j / 2j+1   : h_j hi / lo   (j = 0..51; j>=50 are dead columns, A=0)
//   k=104+2i/105+2i: x_i hi / lo  (i = 0..8)
//   k=122 / 123   : bias hi / lo  (B holds 1.0 in both)
//   k=124..127    : zero pad

typedef __bf16 bf16x8_t __attribute__((ext_vector_type(8)));
typedef float  f32x4_t  __attribute__((ext_vector_type(4)));

// cold-path exact-RNE bf16 (used for weights only)
__device__ __forceinline__ unsigned short bf16_rne(float f) {
  unsigned u = __builtin_bit_cast(unsigned, f);
  unsigned r = (u + 0x7FFFu + ((u >> 16) & 1u)) >> 16;
  return (unsigned short)r;
}
// hot-path: hardware converts; hi/lo pair packed into one u32 (lo in high half)
__device__ __forceinline__ unsigned pack_hilo(float v) {
  __bf16 hi = (__bf16)v;
  float  hf = (float)hi;
  __bf16 lo = (__bf16)(v - hf);
  return ((unsigned)__builtin_bit_cast(unsigned short, lo) << 16) |
         (unsigned)__builtin_bit_cast(unsigned short, hi);
}
__device__ __forceinline__ float sigm_f(float z) {
  float e = __builtin_amdgcn_exp2f(z * -1.44269504088896340736f);
  return __builtin_amdgcn_rcpf(1.0f + e);
}
__device__ __forceinline__ float tanh_f(float z) {
  float e = __builtin_amdgcn_exp2f(z * 2.88539008177792681472f);
  return fmaf(-2.0f, __builtin_amdgcn_rcpf(1.0f + e), 1.0f);
}

__global__ __launch_bounds__(NTH, 1) void lstm_mfma(
    const float* __restrict__ x,
    const float* __restrict__ w_ih,
    const float* __restrict__ w_hh,
    const float* __restrict__ b_ih,
    const float* __restrict__ b_hh,
    const float* __restrict__ fc_w,
    const float* __restrict__ fc_b,
    float* __restrict__ out) {
  __shared__ __align__(16) unsigned short hbuf[2][NB * KDIM];  // 2 x 4096 B
  __shared__ float redbuf[8][NB];

  const int tid = threadIdx.x;
  const int w   = tid >> 6;
  const int l   = tid & 63;
  const int lb  = l & 15;            // batch column
  const int kq  = l >> 4;            // k-quarter 0..3
  const int b0  = blockIdx.x * NB;
  const bool has2 = (w < 5);         // 13 tiles: wave w owns tile w, and 8+w if w<5
  const int tile0 = w, tile1 = 8 + w;

  // ---- zero both h buffers
  for (int i = tid; i < (2 * NB * KDIM) / 2; i += NTH)
    reinterpret_cast<unsigned*>(hbuf)[i] = 0u;
  __syncthreads();

  // ---- bias-one columns k=122,123 (both buffers, never rewritten)
  if (tid < NB) {
#pragma unroll
    for (int bb = 0; bb < 2; ++bb)
      *(unsigned*)((char*)hbuf[bb] + ((((tid) << 8) + 244) ^ ((tid & 7) << 4))) = 0x3F803F80u;
  }

  // ---- x(t=0) into buf0
  const int xb = tid / ISZ, xi = tid - xb * ISZ;
  const bool xact = (tid < NB * ISZ);
  if (xact) {
    float xv = x[(size_t)(b0 + xb) * (TT * ISZ) + xi];
    *(unsigned*)((char*)hbuf[0] + (((xb << 8) + 208 + (xi << 2)) ^ ((xb & 7) << 4))) = pack_hilo(xv);
  }

  // ---- static A fragments (weights, exact-RNE). Row permutation r' = 4j+g:
  // C/D layout (col=lane&15, row=(lane>>4)*4+reg) -> lane's 4 acc regs = (i,f,g,o) of one j.
  bf16x8_t afrag[2][4];
#pragma unroll
  for (int tt = 0; tt < 2; ++tt) {
    const int tile = tt ? tile1 : tile0;
    const bool act = (tt == 0) || has2;
    const int rp  = tile * 16 + lb;
    const int j   = rp >> 2;
    const int g   = rp & 3;
    const int row = g * HH + j;
    const bool live = act && (j < HH);
    float bsum = live ? (b_ih[row] + b_hh[row]) : 0.0f;
    unsigned short bs_hi = bf16_rne(bsum);
    float bs_lo = bsum - __builtin_bit_cast(float, (unsigned)bs_hi << 16);
#pragma unroll
    for (int ks = 0; ks < 4; ++ks) {
#pragma unroll
      for (int e = 0; e < 8; ++e) {
        const int K = ks * 32 + kq * 8 + e;
        unsigned short bits = 0;
        if (live) {
          if (K < 104)      { const int jj = K >> 1; if (jj < HH) bits = bf16_rne(w_hh[row * HH + jj]); }
          else if (K < 122) { const int ii = (K - 104) >> 1; bits = bf16_rne(w_ih[row * ISZ + ii]); }
          else if (K == 122) bits = bs_hi;
          else if (K == 123) bits = bf16_rne(bs_lo);
        }
        afrag[tt][ks][e] = __builtin_bit_cast(__bf16, bits);
      }
    }
  }

  // ---- precomputed LDS byte addresses (toggle ^0x1000 per step)
  char* const base = (char*)hbuf[0];
  const int swzb = (lb & 7) << 4;
  int rd0 = ((lb << 8) + 0   + (kq << 4)) ^ swzb;   // reads: buf0 first
  int rd1 = ((lb << 8) + 64  + (kq << 4)) ^ swzb;
  int rd2 = ((lb << 8) + 128 + (kq << 4)) ^ swzb;
  int rd3 = ((lb << 8) + 192 + (kq << 4)) ^ swzb;
  const int j0 = tile0 * 4 + kq;
  const int j1 = tile1 * 4 + kq;
  int wo0 = ((((lb << 8) + (j0 << 2)) ^ swzb)) + 0x1000;   // writes: buf1 first
  int wo1 = ((((lb << 8) + (j1 << 2)) ^ swzb)) + 0x1000;
  int xwo = ((((xb << 8) + 208 + (xi << 2)) ^ ((xb & 7) << 4))) + 0x1000;

  const float* xp = x + (size_t)(b0 + xb) * (TT * ISZ) + xi + ISZ;  // x(t+1)

  float c0 = 0.0f, c1 = 0.0f, h0 = 0.0f, h1 = 0.0f;

  for (int t = 0; t < TT; ++t) {
    float xv = 0.0f;
    if (xact && (t + 1) < TT) xv = *xp;
    xp += ISZ;

    __syncthreads();   // buf[t&1] now complete

    bf16x8_t bfr0 = *(const bf16x8_t*)(base + rd0);
    bf16x8_t bfr1 = *(const bf16x8_t*)(base + rd1);
    bf16x8_t bfr2 = *(const bf16x8_t*)(base + rd2);
    bf16x8_t bfr3 = *(const bf16x8_t*)(base + rd3);

    f32x4_t acc0 = {0.f, 0.f, 0.f, 0.f};
    f32x4_t acc1 = {0.f, 0.f, 0.f, 0.f};
    acc0 = __builtin_amdgcn_mfma_f32_16x16x32_bf16(afrag[0][0], bfr0, acc0, 0, 0, 0);
    if (has2) acc1 = __builtin_amdgcn_mfma_f32_16x16x32_bf16(afrag[1][0], bfr0, acc1, 0, 0, 0);
    acc0 = __builtin_amdgcn_mfma_f32_16x16x32_bf16(afrag[0][1], bfr1, acc0, 0, 0, 0);
    if (has2) acc1 = __builtin_amdgcn_mfma_f32_16x16x32_bf16(afrag[1][1], bfr1, acc1, 0, 0, 0);
    acc0 = __builtin_amdgcn_mfma_f32_16x16x32_bf16(afrag[0][2], bfr2, acc0, 0, 0, 0);
    if (has2) acc1 = __builtin_amdgcn_mfma_f32_16x16x32_bf16(afrag[1][2], bfr2, acc1, 0, 0, 0);
    acc0 = __builtin_amdgcn_mfma_f32_16x16x32_bf16(afrag[0][3], bfr3, acc0, 0, 0, 0);
    if (has2) acc1 = __builtin_amdgcn_mfma_f32_16x16x32_bf16(afrag[1][3], bfr3, acc1, 0, 0, 0);

    {
      const float iv = sigm_f(acc0[0]), fv = sigm_f(acc0[1]);
      const float gv = tanh_f(acc0[2]), ov = sigm_f(acc0[3]);
      c0 = fmaf(fv, c0, iv * gv);
      h0 = ov * tanh_f(c0);
      *(unsigned*)(base + wo0) = pack_hilo(h0);
    }
    if (has2) {
      const float iv = sigm_f(acc1[0]), fv = sigm_f(acc1[1]);
      const float gv = tanh_f(acc1[2]), ov = sigm_f(acc1[3]);
      c1 = fmaf(fv, c1, iv * gv);
      h1 = ov * tanh_f(c1);
      *(unsigned*)(base + wo1) = pack_hilo(h1);
    }
    if (xact && (t + 1) < TT)
      *(unsigned*)(base + xwo) = pack_hilo(xv);

    rd0 ^= 0x1000; rd1 ^= 0x1000; rd2 ^= 0x1000; rd3 ^= 0x1000;
    wo0 ^= 0x1000; wo1 ^= 0x1000; xwo ^= 0x1000;
  }

  // ---- FC epilogue
  float p = 0.0f;
  if (j0 < HH) p += h0 * fc_w[j0];
  if (has2 && j1 < HH) p += h1 * fc_w[j1];
  p += __shfl_xor(p, 16);
  p += __shfl_xor(p, 32);
  if (l < NB) redbuf[w][l] = p;
  __syncthreads();
  if (tid < NB) {
    float a = fc_b[0];
#pragma unroll
    for (int ww = 0; ww < 8; ++ww) a += redbuf[ww][tid];
    out[b0 + tid] = a;
  }
}

extern "C" void kernel_launch(void* const* d_in, const int* in_sizes, int n_in,
                              void* d_out, int out_size, void* d_ws, size_t ws_size,
                              hipStream_t stream) {
  const float* x    = (const float*)d_in[0];
  const float* w_ih = (const float*)d_in[1];
  const float* w_hh = (const float*)d_in[2];
  const float* b_ih = (const float*)d_in[3];
  const float* b_hh = (const float*)d_in[4];
  const float* fc_w = (const float*)d_in[5];
  const float* fc_b = (const float*)d_in[6];
  float* out = (float*)d_out;
  const int Btot = in_sizes[0] / (TT * ISZ);   // 4096
  dim3 grid(Btot / NB), block(NTH);
  hipLaunchKernelGGL(lstm_mfma, grid, block, 0, stream,
                     x, w_ih, w_hh, b_ih, b_hh, fc_w, fc_b, out);
}